// Round 1
// baseline (50.956 us; speedup 1.0000x reference)
//
#include <hip/hip_runtime.h>
#include <math.h>

// Causal depthwise conv1d (K=4) + SiLU.
// x: (B,T,C) f32, weight: (C,K) f32, bias: (C,) f32 -> out: (B,T,C) f32
// y[b,t,c] = bias[c] + sum_k w[c,k] * x[b, t-K+1+k, c];  out = silu(y)

constexpr int KSZ   = 4;
constexpr int TT    = 16;   // time steps per thread (register sliding window)
constexpr int BLOCK = 256;  // threads per block (multiple of wave=64)

__device__ __forceinline__ float silu_f(float y) {
    // y * sigmoid(y) = y / (1 + exp(-y)); fast rcp is plenty accurate here
    return y * __builtin_amdgcn_rcpf(1.0f + __expf(-y));
}

__global__ __launch_bounds__(BLOCK) void dwconv_silu_kernel(
    const float* __restrict__ x, const float* __restrict__ w,
    const float* __restrict__ bias, float* __restrict__ out,
    int T, int C) {

    const int b  = blockIdx.z;
    const int t0 = blockIdx.y * TT;
    const int c4 = (blockIdx.x * BLOCK + threadIdx.x) * 4;  // 4 channels/thread
    if (c4 >= C) return;

    // Per-channel taps: w[(c)*K .. ] is 4 contiguous floats = one float4.
    const float4 w0 = *reinterpret_cast<const float4*>(w + (size_t)(c4 + 0) * KSZ);
    const float4 w1 = *reinterpret_cast<const float4*>(w + (size_t)(c4 + 1) * KSZ);
    const float4 w2 = *reinterpret_cast<const float4*>(w + (size_t)(c4 + 2) * KSZ);
    const float4 w3 = *reinterpret_cast<const float4*>(w + (size_t)(c4 + 3) * KSZ);
    const float4 bv = *reinterpret_cast<const float4*>(bias + c4);

    const float* xb = x   + (size_t)b * T * C + c4;
    float*       ob = out + (size_t)b * T * C + c4;

    // Sliding window of the 3 previous time steps (zero for t<0: causal pad).
    float4 xm3 = make_float4(0.f, 0.f, 0.f, 0.f);
    float4 xm2 = xm3, xm1 = xm3;
    if (t0 - 3 >= 0) xm3 = *reinterpret_cast<const float4*>(xb + (size_t)(t0 - 3) * C);
    if (t0 - 2 >= 0) xm2 = *reinterpret_cast<const float4*>(xb + (size_t)(t0 - 2) * C);
    if (t0 - 1 >= 0) xm1 = *reinterpret_cast<const float4*>(xb + (size_t)(t0 - 1) * C);

#pragma unroll
    for (int tt = 0; tt < TT; ++tt) {
        const int t = t0 + tt;
        if (t >= T) break;
        const float4 xc = *reinterpret_cast<const float4*>(xb + (size_t)t * C);

        float4 y;
        y.x = bv.x + w0.x * xm3.x + w0.y * xm2.x + w0.z * xm1.x + w0.w * xc.x;
        y.y = bv.y + w1.x * xm3.y + w1.y * xm2.y + w1.z * xm1.y + w1.w * xc.y;
        y.z = bv.z + w2.x * xm3.z + w2.y * xm2.z + w2.z * xm1.z + w2.w * xc.z;
        y.w = bv.w + w3.x * xm3.w + w3.y * xm2.w + w3.z * xm1.w + w3.w * xc.w;

        float4 o;
        o.x = silu_f(y.x);
        o.y = silu_f(y.y);
        o.z = silu_f(y.z);
        o.w = silu_f(y.w);
        *reinterpret_cast<float4*>(ob + (size_t)t * C) = o;

        xm3 = xm2; xm2 = xm1; xm1 = xc;  // shift window
    }
}

extern "C" void kernel_launch(void* const* d_in, const int* in_sizes, int n_in,
                              void* d_out, int out_size, void* d_ws, size_t ws_size,
                              hipStream_t stream) {
    const float* x    = (const float*)d_in[0];
    const float* w    = (const float*)d_in[1];
    const float* bias = (const float*)d_in[2];
    float*       out  = (float*)d_out;

    const int C  = in_sizes[2];          // 2048
    const int BT = in_sizes[0] / C;      // B*T = 16384
    int T = 4096;
    if (BT % T != 0) T = BT;             // fallback: treat as single batch
    const int B = BT / T;

    dim3 block(BLOCK);
    dim3 grid((C + 4 * BLOCK - 1) / (4 * BLOCK),  // channel tiles (2)
              (T + TT - 1) / TT,                  // time tiles (256)
              B);                                 // batch (4)

    dwconv_silu_kernel<<<grid, block, 0, stream>>>(x, w, bias, out, T, C);
}

// Round 3
// 49.053 us; speedup vs baseline: 1.0388x; 1.0388x over previous
//
#include <hip/hip_runtime.h>
#include <math.h>

// Causal depthwise conv1d (K=4) + SiLU.
// x: (B,T,C) f32, weight: (C,K) f32, bias: (C,) f32 -> out: (B,T,C) f32
// y[b,t,c] = bias[c] + sum_k w[c,k] * x[b, t-K+1+k, c];  out = silu(y)

constexpr int KSZ   = 4;
constexpr int TT    = 16;   // time steps per thread
constexpr int BLOCK = 256;  // threads per block (multiple of wave=64)

typedef float floatx4 __attribute__((ext_vector_type(4)));  // native vector for nontemporal store

__device__ __forceinline__ float silu_f(float y) {
    return y * __builtin_amdgcn_rcpf(1.0f + __expf(-y));
}

__global__ __launch_bounds__(BLOCK) void dwconv_silu_kernel(
    const float* __restrict__ x, const float* __restrict__ w,
    const float* __restrict__ bias, float* __restrict__ out,
    int T, int C) {

    const int b  = blockIdx.z;
    const int t0 = blockIdx.y * TT;
    const int c4 = (blockIdx.x * BLOCK + threadIdx.x) * 4;  // 4 channels/thread
    if (c4 >= C) return;

    const float4 w0 = *reinterpret_cast<const float4*>(w + (size_t)(c4 + 0) * KSZ);
    const float4 w1 = *reinterpret_cast<const float4*>(w + (size_t)(c4 + 1) * KSZ);
    const float4 w2 = *reinterpret_cast<const float4*>(w + (size_t)(c4 + 2) * KSZ);
    const float4 w3 = *reinterpret_cast<const float4*>(w + (size_t)(c4 + 3) * KSZ);
    const float4 bv = *reinterpret_cast<const float4*>(bias + c4);

    const float* xb = x   + (size_t)b * T * C + c4;
    float*       ob = out + (size_t)b * T * C + c4;

    const float4 zero = make_float4(0.f, 0.f, 0.f, 0.f);

    if (t0 + TT <= T) {
        // -------- fast path: preload the whole tile (TT+3 float4) --------
        float4 xs[TT + 3];
        // history (zero-pad for t<0; only blockIdx.y==0 hits the guards)
        xs[0] = (t0 - 3 >= 0) ? *reinterpret_cast<const float4*>(xb + (size_t)(t0 - 3) * C) : zero;
        xs[1] = (t0 - 2 >= 0) ? *reinterpret_cast<const float4*>(xb + (size_t)(t0 - 2) * C) : zero;
        xs[2] = (t0 - 1 >= 0) ? *reinterpret_cast<const float4*>(xb + (size_t)(t0 - 1) * C) : zero;
#pragma unroll
        for (int tt = 0; tt < TT; ++tt)
            xs[tt + 3] = *reinterpret_cast<const float4*>(xb + (size_t)(t0 + tt) * C);

#pragma unroll
        for (int tt = 0; tt < TT; ++tt) {
            const float4 a = xs[tt + 0];
            const float4 bq = xs[tt + 1];
            const float4 cq = xs[tt + 2];
            const float4 d = xs[tt + 3];
            float4 y;
            y.x = bv.x + w0.x * a.x + w0.y * bq.x + w0.z * cq.x + w0.w * d.x;
            y.y = bv.y + w1.x * a.y + w1.y * bq.y + w1.z * cq.y + w1.w * d.y;
            y.z = bv.z + w2.x * a.z + w2.y * bq.z + w2.z * cq.z + w2.w * d.z;
            y.w = bv.w + w3.x * a.w + w3.y * bq.w + w3.z * cq.w + w3.w * d.w;
            floatx4 o;
            o.x = silu_f(y.x);
            o.y = silu_f(y.y);
            o.z = silu_f(y.z);
            o.w = silu_f(y.w);
            __builtin_nontemporal_store(o, reinterpret_cast<floatx4*>(ob + (size_t)(t0 + tt) * C));
        }
    } else {
        // -------- tail path: guarded sliding window --------
        float4 xm3 = (t0 - 3 >= 0) ? *reinterpret_cast<const float4*>(xb + (size_t)(t0 - 3) * C) : zero;
        float4 xm2 = (t0 - 2 >= 0) ? *reinterpret_cast<const float4*>(xb + (size_t)(t0 - 2) * C) : zero;
        float4 xm1 = (t0 - 1 >= 0) ? *reinterpret_cast<const float4*>(xb + (size_t)(t0 - 1) * C) : zero;
        for (int tt = 0; tt < TT; ++tt) {
            const int t = t0 + tt;
            if (t >= T) break;
            const float4 xc = *reinterpret_cast<const float4*>(xb + (size_t)t * C);
            float4 y;
            y.x = bv.x + w0.x * xm3.x + w0.y * xm2.x + w0.z * xm1.x + w0.w * xc.x;
            y.y = bv.y + w1.x * xm3.y + w1.y * xm2.y + w1.z * xm1.y + w1.w * xc.y;
            y.z = bv.z + w2.x * xm3.z + w2.y * xm2.z + w2.z * xm1.z + w2.w * xc.z;
            y.w = bv.w + w3.x * xm3.w + w3.y * xm2.w + w3.z * xm1.w + w3.w * xc.w;
            float4 o;
            o.x = silu_f(y.x);
            o.y = silu_f(y.y);
            o.z = silu_f(y.z);
            o.w = silu_f(y.w);
            *reinterpret_cast<float4*>(ob + (size_t)t * C) = o;
            xm3 = xm2; xm2 = xm1; xm1 = xc;
        }
    }
}

extern "C" void kernel_launch(void* const* d_in, const int* in_sizes, int n_in,
                              void* d_out, int out_size, void* d_ws, size_t ws_size,
                              hipStream_t stream) {
    const float* x    = (const float*)d_in[0];
    const float* w    = (const float*)d_in[1];
    const float* bias = (const float*)d_in[2];
    float*       out  = (float*)d_out;

    const int C  = in_sizes[2];          // 2048
    const int BT = in_sizes[0] / C;      // B*T = 16384
    int T = 4096;
    if (BT % T != 0) T = BT;             // fallback: treat as single batch
    const int B = BT / T;

    dim3 block(BLOCK);
    dim3 grid((C + 4 * BLOCK - 1) / (4 * BLOCK),  // channel tiles
              (T + TT - 1) / TT,                  // time tiles
              B);                                 // batch

    dwconv_silu_kernel<<<grid, block, 0, stream>>>(x, w, bias, out, T, C);
}